// Round 18
// baseline (112.109 us; speedup 1.0000x reference)
//
#include <hip/hip_runtime.h>
#include <math.h>

// Problem constants
#define N_  64
#define TC_ 256
#define K_  32
#define TK_ 64
#define D_  256
#define D4_ 64            // float4 per embedding row
#define TF_ 320           // TK + TC
#define V_  32000

// ws layout (float offsets) — every slot written before read, no memset:
//   part   [1024][D]  f32  @ 0        per-(n,16-token-chunk) ctx partial sums
//   clen_p [1024]     int  @ 262144   per-chunk ctx token counts
//   score  [N][K]     f32  @ 263168   ck-masked scores (-inf pad) for argmax
#define WS_CLENP  262144
#define WS_SCORE  263168

__device__ __forceinline__ float4 fmask4(float4 v, int keep) {
    const float m = keep ? 1.f : 0.f;
    float4 r;
    r.x = m * v.x; r.y = m * v.y; r.z = m * v.z; r.w = m * v.w;
    return r;
}

// out_enc is write-once, never re-read by us: non-temporal keeps 21 MB of
// stores from evicting embed rows out of L2/L3 between k1 and k2.
// NOTE: __builtin_nontemporal_store rejects HIP_vector_type (float4); use a
// clang ext_vector_type alias (bit-identical, same dwordx4 store + nt flag).
typedef float nfloat4 __attribute__((ext_vector_type(4)));
__device__ __forceinline__ void nt_store4(float4* p, float4 v) {
    nfloat4 nv;
    nv.x = v.x; nv.y = v.y; nv.z = v.z; nv.w = v.w;
    __builtin_nontemporal_store(nv, (nfloat4*)p);
}

// ---------------------------------------------------------------------------
// k1: ctx gather. grid = N*16 (16 tokens/block), block = 256 (4 waves).
// Branchless row loads (embed[0] valid, masked after); nt stores for out_enc.
// ---------------------------------------------------------------------------
__global__ __launch_bounds__(256) void k1_ctx(
        const int* __restrict__ src, const float4* __restrict__ embed4,
        float4* __restrict__ out_enc4, float* __restrict__ out_mask,
        float4* __restrict__ ws_part4, int* __restrict__ clen_p) {
    const int b = blockIdx.x, n = b >> 4, c = b & 15;
    const int tid = threadIdx.x, w = tid >> 6, l = tid & 63;

    __shared__ int    toks[16];
    __shared__ float4 part[4][64];

    if (tid < 16) {
        const int tok = src[n * TC_ + c * 16 + tid];
        toks[tid] = tok;
        out_mask[n * TF_ + TK_ + c * 16 + tid] = tok ? 1.f : 0.f;
    }
    __syncthreads();

    float4 acc = {0.f, 0.f, 0.f, 0.f};
    #pragma unroll
    for (int i = 0; i < 4; ++i) {                 // wave w: tokens [4w, 4w+4)
        const int t = w * 4 + i;
        const int tok = toks[t];
        const float4 v = fmask4(embed4[(size_t)tok * D4_ + l], tok != 0);
        nt_store4(&out_enc4[((size_t)n * TF_ + TK_ + c * 16 + t) * D4_ + l], v);
        acc.x += v.x; acc.y += v.y; acc.z += v.z; acc.w += v.w;
    }
    part[w][l] = acc;
    __syncthreads();

    if (w == 0) {
        float4 a = part[0][l], b1 = part[1][l], p2 = part[2][l], p3 = part[3][l];
        a.x += b1.x + p2.x + p3.x;  a.y += b1.y + p2.y + p3.y;
        a.z += b1.z + p2.z + p3.z;  a.w += b1.w + p2.w + p3.w;
        ws_part4[(size_t)b * D4_ + l] = a;        // re-read by k2: keep cached
        const unsigned long long ball = __ballot(l < 16 && toks[l] != 0);
        if (l == 0) clen_p[b] = __popcll(ball);
    }
}

// ---------------------------------------------------------------------------
// k2: knowledge scoring, TWO k's per block. grid = N*K/2 = 1024, block = 256.
// Per wave: 32 independent branchless row-loads (16 per k) -> deep VMEM
// pipeline. ctx staged once per block for both k's (halved ws re-reads).
// ---------------------------------------------------------------------------
__global__ __launch_bounds__(256) void k2_know(
        const int* __restrict__ know, const int* __restrict__ ckm,
        const float4* __restrict__ embed4,
        const float4* __restrict__ ws_part4, const int* __restrict__ clen_p,
        float* __restrict__ out_attn, float* __restrict__ ws_score) {
    const int b = blockIdx.x, n = b >> 4, kp = (b & 15) << 1;   // k = kp, kp+1
    const int tid = threadIdx.x, w = tid >> 6, l = tid & 63;

    __shared__ int    ktoks[2][TK_];
    __shared__ float4 cpart[4][64];
    __shared__ float  redp[2][4];
    __shared__ int    lk_sh[2], lc_sh;

    if (tid < 128)
        ktoks[tid >> 6][tid & 63] =
            know[((size_t)n * K_ + kp + (tid >> 6)) * TK_ + (tid & 63)];
    {   // stage ctx sum: wave w sums chunks [4w, 4w+4)
        float4 s = {0.f, 0.f, 0.f, 0.f};
        #pragma unroll
        for (int c = 0; c < 4; ++c) {
            const float4 v = ws_part4[(size_t)(n * 16 + w * 4 + c) * D4_ + l];
            s.x += v.x; s.y += v.y; s.z += v.z; s.w += v.w;
        }
        cpart[w][l] = s;
    }
    if (w == 1) {                                 // reduce ctx length
        int cl = (l < 16) ? clen_p[n * 16 + l] : 0;
        #pragma unroll
        for (int o = 32; o > 0; o >>= 1) cl += __shfl_down(cl, o, 64);
        if (l == 0) lc_sh = cl;
    }
    __syncthreads();

    if (w == 0) {                                 // know lengths (per k)
        const unsigned long long ball = __ballot(ktoks[0][l] != 0);
        if (l == 0) lk_sh[0] = __popcll(ball);
    } else if (w == 2) {
        const unsigned long long ball = __ballot(ktoks[1][l] != 0);
        if (l == 0) lk_sh[1] = __popcll(ball);
    }

    float4 cx = cpart[0][l];
    {
        const float4 c1 = cpart[1][l], c2 = cpart[2][l], c3 = cpart[3][l];
        cx.x += c1.x + c2.x + c3.x;  cx.y += c1.y + c2.y + c3.y;
        cx.z += c1.z + c2.z + c3.z;  cx.w += c1.w + c2.w + c3.w;
    }

    float4 a0 = {0.f, 0.f, 0.f, 0.f}, a1 = {0.f, 0.f, 0.f, 0.f};
    #pragma unroll
    for (int i = 0; i < 16; ++i) {                // wave w: rows [16w, 16w+16)
        const int t0 = ktoks[0][w * 16 + i];
        const int t1 = ktoks[1][w * 16 + i];
        const float4 v0 = embed4[(size_t)t0 * D4_ + l];   // unconditional
        const float4 v1 = embed4[(size_t)t1 * D4_ + l];
        const float m0 = (t0 != 0) ? 1.f : 0.f;
        const float m1 = (t1 != 0) ? 1.f : 0.f;
        a0.x = fmaf(m0, v0.x, a0.x); a0.y = fmaf(m0, v0.y, a0.y);
        a0.z = fmaf(m0, v0.z, a0.z); a0.w = fmaf(m0, v0.w, a0.w);
        a1.x = fmaf(m1, v1.x, a1.x); a1.y = fmaf(m1, v1.y, a1.y);
        a1.z = fmaf(m1, v1.z, a1.z); a1.w = fmaf(m1, v1.w, a1.w);
    }
    float p0 = a0.x * cx.x + a0.y * cx.y + a0.z * cx.z + a0.w * cx.w;
    float p1 = a1.x * cx.x + a1.y * cx.y + a1.z * cx.z + a1.w * cx.w;
    #pragma unroll
    for (int o = 32; o > 0; o >>= 1) {
        p0 += __shfl_down(p0, o, 64);
        p1 += __shfl_down(p1, o, 64);
    }
    if (l == 0) { redp[0][w] = p0; redp[1][w] = p1; }
    __syncthreads();

    if (tid < 2) {
        const float dot = redp[tid][0] + redp[tid][1] + redp[tid][2] + redp[tid][3];
        const int kk = kp + tid;
        const int ck = ckm[n * K_ + kk];
        const int lc = max(lc_sh, 1);
        int lk = ck ? lk_sh[tid] : 0;  if (lk < 1) lk = 1;  // know_mask incl. ck
        const float score =
            dot / (sqrtf((float)(D_ * lc)) * sqrtf((float)(D_ * lk)));
        out_attn[n * K_ + kk] = ck ? score : 0.f;
        ws_score[n * K_ + kk] = ck ? score : -INFINITY;
    }
}

// ---------------------------------------------------------------------------
// k3: argmax-select (first-max tie-break = jnp.argmax) or cs_ids; gather the
// selected span into slots [0, TK). grid = N*4 (16 tokens/block), block = 256.
// ---------------------------------------------------------------------------
__global__ __launch_bounds__(256) void k3_sel(
        const int* __restrict__ know, const int* __restrict__ ckm,
        const int* __restrict__ cs_ids, const int* __restrict__ use_flag,
        const float4* __restrict__ embed4, const float* __restrict__ ws_score,
        float4* __restrict__ out_enc4, float* __restrict__ out_mask) {
    const int n = blockIdx.x >> 2, c = blockIdx.x & 3;
    const int tid = threadIdx.x, w = tid >> 6, l = tid & 63;

    // uniform redundant argmax (32 cached reads; no divergence)
    int cs = 0;
    if (use_flag[0]) {
        cs = cs_ids[n];
    } else {
        float best = -INFINITY;
        #pragma unroll
        for (int j = 0; j < K_; ++j) {
            const float s = ws_score[n * K_ + j];
            if (s > best) { best = s; cs = j; }   // first-max tie-break
        }
    }
    const int ck = ckm[n * K_ + cs];

    __shared__ int toks[16];
    if (tid < 16) {
        const int tok = know[((size_t)n * K_ + cs) * TK_ + c * 16 + tid];
        toks[tid] = tok;
        out_mask[n * TF_ + c * 16 + tid] = (ck && tok) ? 1.f : 0.f;
    }
    __syncthreads();
    #pragma unroll
    for (int i = 0; i < 4; ++i) {                 // wave w: rows [4w, 4w+4)
        const int t = w * 4 + i;
        const int tok = toks[t];
        const float4 v =
            fmask4(embed4[(size_t)tok * D4_ + l], ck && tok != 0);
        nt_store4(&out_enc4[((size_t)n * TF_ + c * 16 + t) * D4_ + l], v);
    }
}

// ---------------------------------------------------------------------------
extern "C" void kernel_launch(void* const* d_in, const int* in_sizes, int n_in,
                              void* d_out, int out_size, void* d_ws, size_t ws_size,
                              hipStream_t stream) {
    const int*   src      = (const int*)d_in[0];    // [N,TC]
    const int*   know     = (const int*)d_in[1];    // [N,K,TK]
    const int*   ckm      = (const int*)d_in[2];    // [N,K]
    const int*   cs_ids   = (const int*)d_in[3];    // [N]
    const int*   use_flag = (const int*)d_in[4];    // scalar
    const float* embed    = (const float*)d_in[5];  // [V,D]

    float* out      = (float*)d_out;
    float* out_mask = out + (size_t)N_ * TF_ * D_;  // [N,TF]
    float* out_attn = out_mask + N_ * TF_;          // [N,K]

    float*  ws       = (float*)d_ws;                // ~1.06 MB used
    float4* ws_part4 = (float4*)ws;
    int*    clen_p   = (int*)(ws + WS_CLENP);
    float*  ws_score = ws + WS_SCORE;

    hipLaunchKernelGGL(k1_ctx, dim3(N_ * 16), dim3(256), 0, stream,
                       src, (const float4*)embed, (float4*)out, out_mask,
                       ws_part4, clen_p);
    hipLaunchKernelGGL(k2_know, dim3(N_ * K_ / 2), dim3(256), 0, stream,
                       know, ckm, (const float4*)embed, ws_part4, clen_p,
                       out_attn, ws_score);
    hipLaunchKernelGGL(k3_sel, dim3(N_ * 4), dim3(256), 0, stream,
                       know, ckm, cs_ids, use_flag, (const float4*)embed,
                       ws_score, (float4*)out, out_mask);
}